// Round 8
// baseline (212.324 us; speedup 1.0000x reference)
//
#include <hip/hip_runtime.h>
#include <hip/hip_bf16.h>

// LSS voxel pooling via inverted index (BEVPool-style), no atomics in gather.
//   x:    (B=8, N=6, D=41, H=16, W=44, C=64) f32
//   geom: (B, N, D, H, W, 3) f32
//   out:  (B, C=64, X=200, Y=200) f32
//
// bin = (b*200 + ix)*200 + iy,  kept iff 0<=ix<200, 0<=iy<200, iz==0
// (IEEE fp32 add + div + trunc-toward-zero matches reference .astype(int32))
//
// Pipeline:
//   A bin_points : bin id per point + histogram (int atomics, L2)
//   B scan       : 2-level exclusive scan; blocksums[] kept SEPARATE
//                  (consumers add blocksums[bin>>8] on the fly); grand total
//                  published at blocksums[NBLK_SCAN]
//   C scatter    : CSR fill; slot from atomicSub on counts (counts dead after
//                  scan; no cursor array)
//   D gather5    : block = half (b,ix) row; wave owns EXCLUSIVE 25-bin CSR
//                  range; 12-deep pipelined plain 256B x loads (L3-friendly),
//                  register accumulation per bin (wave-uniform bin-change),
//                  one plain ds_write per non-empty bin, coalesced out-write.

#define NP        1385472
#define NP_PER_B  173184      // N*D*H*W
#define NXY       200
#define NBIN      320000      // 8*200*200
#define NBLK_SCAN 1250        // NBIN/256 exactly
#define UNR       12          // outstanding x-loads per wave in gather
#define BINS_PER_WAVE 25      // 100 bins per block / 4 waves

// ---------------- phase A: bin each point + histogram ----------------
__global__ void bin_points(const float* __restrict__ geom,
                           int* __restrict__ bins,
                           int* __restrict__ counts) {
    int p = blockIdx.x * 256 + threadIdx.x;
    if (p >= NP) return;
    float gx = geom[(size_t)p * 3 + 0];
    float gy = geom[(size_t)p * 3 + 1];
    float gz = geom[(size_t)p * 3 + 2];
    int ix = (int)((gx + 50.0f) / 0.5f);
    int iy = (int)((gy + 50.0f) / 0.5f);
    int iz = (int)((gz + 10.0f) / 20.0f);
    int bin = -1;
    if (ix >= 0 && ix < NXY && iy >= 0 && iy < NXY && iz == 0) {
        int b = p / NP_PER_B;
        bin = (b * NXY + ix) * NXY + iy;
        atomicAdd(&counts[bin], 1);
    }
    bins[p] = bin;
}

// ---------------- phase B: exclusive scan of counts (2-level) ----------------
__global__ void scan_blocks(const int* __restrict__ counts,
                            int* __restrict__ offsets,
                            int* __restrict__ blocksums) {
    __shared__ int tmp[256];
    int i = blockIdx.x * 256 + threadIdx.x;
    int v = (i < NBIN) ? counts[i] : 0;
    tmp[threadIdx.x] = v;
    __syncthreads();
    for (int d = 1; d < 256; d <<= 1) {
        int t = (threadIdx.x >= d) ? tmp[threadIdx.x - d] : 0;
        __syncthreads();
        tmp[threadIdx.x] += t;
        __syncthreads();
    }
    if (i < NBIN) offsets[i] = tmp[threadIdx.x] - v;   // exclusive, block-local
    if (threadIdx.x == 255) blocksums[blockIdx.x] = tmp[255];
}

__global__ void scan_sums(int* __restrict__ blocksums, int nblocks) {
    __shared__ int tmp[256];
    __shared__ int carry;
    if (threadIdx.x == 0) carry = 0;
    __syncthreads();
    for (int base = 0; base < nblocks; base += 256) {
        int i = base + threadIdx.x;
        int v = (i < nblocks) ? blocksums[i] : 0;
        tmp[threadIdx.x] = v;
        __syncthreads();
        for (int d = 1; d < 256; d <<= 1) {
            int t = (threadIdx.x >= d) ? tmp[threadIdx.x - d] : 0;
            __syncthreads();
            tmp[threadIdx.x] += t;
            __syncthreads();
        }
        if (i < nblocks) blocksums[i] = tmp[threadIdx.x] - v + carry;  // exclusive
        __syncthreads();
        if (threadIdx.x == 255) carry += tmp[255];
        __syncthreads();
    }
    if (threadIdx.x == 0) blocksums[nblocks] = carry;   // grand total (kept pts)
}

// ---------------- phase C: scatter packed (pid,iy) into CSR ----------------
// counts is consumed here (atomicSub to 0); gather derives lengths from the
// next bin's global prefix instead.
__global__ void scatter_idx(const int* __restrict__ bins,
                            const int* __restrict__ offsets,
                            const int* __restrict__ blocksums,
                            int* __restrict__ counts,
                            unsigned int* __restrict__ sorted) {
    int p = blockIdx.x * 256 + threadIdx.x;
    if (p >= NP) return;
    int bin = bins[p];
    if (bin >= 0) {
        int pos = atomicSub(&counts[bin], 1) - 1;        // [0, count)
        int dst = offsets[bin] + blocksums[bin >> 8] + pos;
        sorted[dst] = ((unsigned int)p << 8) | (unsigned int)(bin % NXY);
    }
}

// ------- phase D: atomic-free gather, register accumulation per bin -------
__global__ __launch_bounds__(256, 6) void gather5(const float* __restrict__ x,
                                                  const int* __restrict__ offsets,
                                                  const int* __restrict__ blocksums,
                                                  const unsigned int* __restrict__ packed,
                                                  float* __restrict__ out) {
    __shared__ float tile[64 * 101];   // [c][iy_local], 101: 2-way bank alias only
    for (int f = threadIdx.x; f < 64 * 101; f += 256) tile[f] = 0.0f;
    __syncthreads();

    const int bix   = blockIdx.x >> 1;        // b*200 + ix
    const int half  = blockIdx.x & 1;         // iy half: 0 -> 0..99, 1 -> 100..199
    const int hbase = half * 100;
    const int wave  = threadIdx.x >> 6;
    const int lane  = threadIdx.x & 63;

    // wave-exclusive contiguous CSR range: bins [bin0, bin0+25)
    const int bin0  = bix * NXY + hbase + wave * BINS_PER_WAVE;
    const int binE1 = bin0 + BINS_PER_WAVE;
    const int ps = offsets[bin0] + blocksums[bin0 >> 8];
    const int pe = (binE1 < NBIN) ? (offsets[binE1] + blocksums[binE1 >> 8])
                                  : blocksums[NBLK_SCAN];

    int   cur = -1;       // current global iy being accumulated (wave-uniform)
    float acc = 0.0f;     // per-lane accumulator for channel `lane` of bin cur

    int i = ps;
    unsigned int pk[UNR];
    bool have = (i + UNR <= pe);
    if (have) {
#pragma unroll
        for (int u = 0; u < UNR; ++u) pk[u] = packed[i + u];
    }
    while (have) {
        // UNR independent 256B x-row loads (plain: let L2/L3 cache x across
        // replays -- measured 50% L3 hit on this stream)
        float v[UNR];
#pragma unroll
        for (int u = 0; u < UNR; ++u)
            v[u] = x[(size_t)(pk[u] >> 8) * 64 + lane];

        // software-pipeline next pk batch while x loads are in flight
        const int ni = i + UNR;
        const bool have2 = (ni + UNR <= pe);
        unsigned int pk2[UNR];
        if (have2) {
#pragma unroll
            for (int u = 0; u < UNR; ++u) pk2[u] = packed[ni + u];
        }

        // register accumulation; bin-change is wave-uniform (scalar branch)
#pragma unroll
        for (int u = 0; u < UNR; ++u) {
            const int iy = (int)(__builtin_amdgcn_readfirstlane(pk[u]) & 0xFFu);
            if (iy != cur) {
                if (cur >= 0) tile[lane * 101 + (cur - hbase)] = acc;  // plain ds_write
                cur = iy;
                acc = v[u];
            } else {
                acc += v[u];
            }
        }

#pragma unroll
        for (int u = 0; u < UNR; ++u) pk[u] = pk2[u];
        i = ni;
        have = have2;
    }
    // tail (< UNR points)
    for (; i < pe; ++i) {
        const unsigned int p = packed[i];
        const float vv = x[(size_t)(p >> 8) * 64 + lane];
        const int iy = (int)(__builtin_amdgcn_readfirstlane(p) & 0xFFu);
        if (iy != cur) {
            if (cur >= 0) tile[lane * 101 + (cur - hbase)] = acc;
            cur = iy;
            acc = vv;
        } else {
            acc += vv;
        }
    }
    if (cur >= 0) tile[lane * 101 + (cur - hbase)] = acc;  // final flush
    __syncthreads();

    const int b  = bix / NXY;
    const int ix = bix % NXY;
    float* obase = out + (size_t)b * 64 * 40000 + (size_t)ix * 200 + hbase;
    for (int f = threadIdx.x; f < 64 * 100; f += 256) {
        const int c  = f / 100;
        const int iy = f % 100;
        obase[(size_t)c * 40000 + iy] = tile[c * 101 + iy];
    }
}

// ---------------- fallback (round-1): direct atomic scatter ----------------
__global__ void lss_scatter_atomic(const float* __restrict__ x,
                                   const float* __restrict__ geom,
                                   float* __restrict__ out) {
    const int lane   = threadIdx.x & 63;
    const int wave   = (blockIdx.x * blockDim.x + threadIdx.x) >> 6;
    const int nwaves = (gridDim.x * blockDim.x) >> 6;
    for (int p = wave; p < NP; p += nwaves) {
        const float gx = geom[(size_t)p * 3 + 0];
        const float gy = geom[(size_t)p * 3 + 1];
        const float gz = geom[(size_t)p * 3 + 2];
        const int ix = (int)((gx + 50.0f) / 0.5f);
        const int iy = (int)((gy + 50.0f) / 0.5f);
        const int iz = (int)((gz + 10.0f) / 20.0f);
        if (ix >= 0 && ix < NXY && iy >= 0 && iy < NXY && iz == 0) {
            const int b = p / NP_PER_B;
            const float v = x[(size_t)p * 64 + lane];
            atomicAdd(&out[(((size_t)b * 64 + lane) * NXY + ix) * NXY + iy], v);
        }
    }
}

extern "C" void kernel_launch(void* const* d_in, const int* in_sizes, int n_in,
                              void* d_out, int out_size, void* d_ws, size_t ws_size,
                              hipStream_t stream) {
    const float* x    = (const float*)d_in[0];
    const float* geom = (const float*)d_in[1];
    float* out = (float*)d_out;

    // workspace carve-up
    char* ws = (char*)d_ws;
    size_t off = 0;
    int* counts    = (int*)(ws + off); off += (size_t)NBIN * 4;
    int* offsets   = (int*)(ws + off); off += (size_t)NBIN * 4;
    int* blocksums = (int*)(ws + off); off += (size_t)(NBLK_SCAN + 1) * 4;
    int* bins      = (int*)(ws + off); off += (size_t)NP * 4;
    unsigned int* sorted = (unsigned int*)(ws + off); off += (size_t)NP * 4;

    if (ws_size < off) {
        // fallback: direct atomic scatter
        hipMemsetAsync(out, 0, (size_t)out_size * sizeof(float), stream);
        lss_scatter_atomic<<<2048, 256, 0, stream>>>(x, geom, out);
        return;
    }

    hipMemsetAsync(counts, 0, (size_t)NBIN * 4, stream);

    const int pblocks = (NP + 255) / 256;                 // 5412
    bin_points<<<pblocks, 256, 0, stream>>>(geom, bins, counts);
    scan_blocks<<<NBLK_SCAN, 256, 0, stream>>>(counts, offsets, blocksums);
    scan_sums<<<1, 256, 0, stream>>>(blocksums, NBLK_SCAN);
    scatter_idx<<<pblocks, 256, 0, stream>>>(bins, offsets, blocksums, counts, sorted);
    gather5<<<2 * 8 * NXY, 256, 0, stream>>>(x, offsets, blocksums, sorted, out);
}

// Round 9
// 194.687 us; speedup vs baseline: 1.0906x; 1.0906x over previous
//
#include <hip/hip_runtime.h>
#include <hip/hip_bf16.h>

// LSS voxel pooling via inverted index (BEVPool-style), no atomics in gather.
//   x:    (B=8, N=6, D=41, H=16, W=44, C=64) f32
//   geom: (B, N, D, H, W, 3) f32
//   out:  (B, C=64, X=200, Y=200) f32
//
// bin = (b*200 + ix)*200 + iy,  kept iff 0<=ix<200, 0<=iy<200, iz==0
// (IEEE fp32 add + div + trunc-toward-zero matches reference .astype(int32))
//
// Pipeline:
//   A bin_points : bin id per point + histogram (int atomics, L2)
//   B scan       : 2-level exclusive scan; blocksums[] separate (consumers add
//                  blocksums[bin>>8]); grand total at blocksums[NBLK_SCAN]
//   C scatter    : CSR fill; slot via atomicSub on counts (no cursor array)
//   D gather6    : block = half (b,ix) row (100 bins). QUARTER-WAVE parallel:
//                  lane = (q = lane>>4, sl = lane&15); quarter owns an
//                  exclusive 6-7 bin CSR range; each wave step processes 4
//                  points with float4 lanes (1KB per VMEM instr), branchless
//                  bin-change (cndmask + exec-masked flush), register float4
//                  accumulator, one 4xds_write_b32 flush per non-empty bin.

#define NP        1385472
#define NP_PER_B  173184      // N*D*H*W
#define NXY       200
#define NBIN      320000      // 8*200*200
#define NBLK_SCAN 1250        // NBIN/256 exactly
#define UNR       8           // point-steps in flight per wave (4 pts each)
#define TSTRIDE   69          // tile row stride in floats (odd -> no bank conflict)

// ---------------- phase A: bin each point + histogram ----------------
__global__ void bin_points(const float* __restrict__ geom,
                           int* __restrict__ bins,
                           int* __restrict__ counts) {
    int p = blockIdx.x * 256 + threadIdx.x;
    if (p >= NP) return;
    float gx = geom[(size_t)p * 3 + 0];
    float gy = geom[(size_t)p * 3 + 1];
    float gz = geom[(size_t)p * 3 + 2];
    int ix = (int)((gx + 50.0f) / 0.5f);
    int iy = (int)((gy + 50.0f) / 0.5f);
    int iz = (int)((gz + 10.0f) / 20.0f);
    int bin = -1;
    if (ix >= 0 && ix < NXY && iy >= 0 && iy < NXY && iz == 0) {
        int b = p / NP_PER_B;
        bin = (b * NXY + ix) * NXY + iy;
        atomicAdd(&counts[bin], 1);
    }
    bins[p] = bin;
}

// ---------------- phase B: exclusive scan of counts (2-level) ----------------
__global__ void scan_blocks(const int* __restrict__ counts,
                            int* __restrict__ offsets,
                            int* __restrict__ blocksums) {
    __shared__ int tmp[256];
    int i = blockIdx.x * 256 + threadIdx.x;
    int v = (i < NBIN) ? counts[i] : 0;
    tmp[threadIdx.x] = v;
    __syncthreads();
    for (int d = 1; d < 256; d <<= 1) {
        int t = (threadIdx.x >= d) ? tmp[threadIdx.x - d] : 0;
        __syncthreads();
        tmp[threadIdx.x] += t;
        __syncthreads();
    }
    if (i < NBIN) offsets[i] = tmp[threadIdx.x] - v;   // exclusive, block-local
    if (threadIdx.x == 255) blocksums[blockIdx.x] = tmp[255];
}

__global__ void scan_sums(int* __restrict__ blocksums, int nblocks) {
    __shared__ int tmp[256];
    __shared__ int carry;
    if (threadIdx.x == 0) carry = 0;
    __syncthreads();
    for (int base = 0; base < nblocks; base += 256) {
        int i = base + threadIdx.x;
        int v = (i < nblocks) ? blocksums[i] : 0;
        tmp[threadIdx.x] = v;
        __syncthreads();
        for (int d = 1; d < 256; d <<= 1) {
            int t = (threadIdx.x >= d) ? tmp[threadIdx.x - d] : 0;
            __syncthreads();
            tmp[threadIdx.x] += t;
            __syncthreads();
        }
        if (i < nblocks) blocksums[i] = tmp[threadIdx.x] - v + carry;  // exclusive
        __syncthreads();
        if (threadIdx.x == 255) carry += tmp[255];
        __syncthreads();
    }
    if (threadIdx.x == 0) blocksums[nblocks] = carry;   // grand total (kept pts)
}

// ---------------- phase C: scatter packed (pid,iy) into CSR ----------------
__global__ void scatter_idx(const int* __restrict__ bins,
                            const int* __restrict__ offsets,
                            const int* __restrict__ blocksums,
                            int* __restrict__ counts,
                            unsigned int* __restrict__ sorted) {
    int p = blockIdx.x * 256 + threadIdx.x;
    if (p >= NP) return;
    int bin = bins[p];
    if (bin >= 0) {
        int pos = atomicSub(&counts[bin], 1) - 1;        // [0, count)
        int dst = offsets[bin] + blocksums[bin >> 8] + pos;
        sorted[dst] = ((unsigned int)p << 8) | (unsigned int)(bin % NXY);
    }
}

// ------- phase D: quarter-wave float4 gather, branchless bin tracking -------
__global__ __launch_bounds__(256, 4) void gather6(const float* __restrict__ x,
                                                  const int* __restrict__ offsets,
                                                  const int* __restrict__ blocksums,
                                                  const unsigned int* __restrict__ packed,
                                                  float* __restrict__ out) {
    __shared__ float tile[100 * TSTRIDE];   // [iy_local][c], stride 69
    for (int f = threadIdx.x; f < 100 * TSTRIDE; f += 256) tile[f] = 0.0f;
    __syncthreads();

    const float4* __restrict__ x4 = (const float4*)x;

    const int bix   = blockIdx.x >> 1;        // b*200 + ix
    const int half  = blockIdx.x & 1;         // iy half: 0 -> 0..99, 1 -> 100..199
    const int hbase = half * 100;
    const int wave  = threadIdx.x >> 6;
    const int lane  = threadIdx.x & 63;
    const int q     = lane >> 4;              // quarter-wave 0..3
    const int sl    = lane & 15;              // sub-lane: channels 4*sl..4*sl+3

    // quarter-exclusive contiguous bin range within the wave's 25 bins:
    // q=0 -> 7 bins, q=1..3 -> 6 bins
    const int bin0w = bix * NXY + hbase + wave * 25;
    const int qs = bin0w + (q ? 6 * q + 1 : 0);
    const int qe = qs + (q ? 6 : 7);
    const int ps = offsets[qs] + blocksums[qs >> 8];
    const int pe = (qe < NBIN) ? (offsets[qe] + blocksums[qe >> 8])
                               : blocksums[NBLK_SCAN];

    int   cur = -1;                 // current global iy (uniform within quarter)
    float ax = 0.f, ay = 0.f, az = 0.f, aw = 0.f;

    int i = ps;
    unsigned int pk[UNR];
#pragma unroll
    for (int u = 0; u < UNR; ++u) {
        int ii = i + u; ii = (ii < pe) ? ii : (pe - 1); ii = (ii < 0) ? 0 : ii;
        pk[u] = packed[ii];                        // clamped -> always in-bounds
    }
    while (__any(i < pe)) {
        // UNR independent 1KB x loads (4 rows per wave instruction)
        float4 v[UNR];
#pragma unroll
        for (int u = 0; u < UNR; ++u) {
            const bool val = (i + u) < pe;
            const unsigned int pid = val ? (pk[u] >> 8) : 0u;
            v[u] = x4[(size_t)pid * 16 + sl];
        }
        // prefetch next pk batch (clamped, branchless)
        const int ni = i + UNR;
        unsigned int pk2[UNR];
#pragma unroll
        for (int u = 0; u < UNR; ++u) {
            int ii = ni + u; ii = (ii < pe) ? ii : (pe - 1); ii = (ii < 0) ? 0 : ii;
            pk2[u] = packed[ii];
        }
        // branchless per-quarter accumulation
#pragma unroll
        for (int u = 0; u < UNR; ++u) {
            const bool val = (i + u) < pe;
            const int iyv  = val ? (int)(pk[u] & 0xFFu) : cur;   // invalid -> no change
            const bool chg = (iyv != cur);
            if (chg && cur >= 0) {                // exec-masked flush (4x ds_write_b32)
                const int ba = (cur - hbase) * TSTRIDE + sl * 4;
                tile[ba + 0] = ax; tile[ba + 1] = ay;
                tile[ba + 2] = az; tile[ba + 3] = aw;
            }
            const float mx = val ? v[u].x : 0.f;
            const float my = val ? v[u].y : 0.f;
            const float mz = val ? v[u].z : 0.f;
            const float mw = val ? v[u].w : 0.f;
            ax = chg ? v[u].x : ax + mx;          // chg implies val
            ay = chg ? v[u].y : ay + my;
            az = chg ? v[u].z : az + mz;
            aw = chg ? v[u].w : aw + mw;
            cur = chg ? iyv : cur;
        }
#pragma unroll
        for (int u = 0; u < UNR; ++u) pk[u] = pk2[u];
        i = ni;
    }
    if (cur >= 0) {                               // final flush
        const int ba = (cur - hbase) * TSTRIDE + sl * 4;
        tile[ba + 0] = ax; tile[ba + 1] = ay;
        tile[ba + 2] = az; tile[ba + 3] = aw;
    }
    __syncthreads();

    // coalesced out-write: consecutive threads -> consecutive iy
    const int b  = bix / NXY;
    const int ix = bix % NXY;
    float* obase = out + (size_t)b * 64 * 40000 + (size_t)ix * 200 + hbase;
    for (int f = threadIdx.x; f < 64 * 100; f += 256) {
        const int c  = f / 100;
        const int iy = f % 100;
        obase[(size_t)c * 40000 + iy] = tile[iy * TSTRIDE + c];  // stride 69: conflict-free
    }
}

// ---------------- fallback (round-1): direct atomic scatter ----------------
__global__ void lss_scatter_atomic(const float* __restrict__ x,
                                   const float* __restrict__ geom,
                                   float* __restrict__ out) {
    const int lane   = threadIdx.x & 63;
    const int wave   = (blockIdx.x * blockDim.x + threadIdx.x) >> 6;
    const int nwaves = (gridDim.x * blockDim.x) >> 6;
    for (int p = wave; p < NP; p += nwaves) {
        const float gx = geom[(size_t)p * 3 + 0];
        const float gy = geom[(size_t)p * 3 + 1];
        const float gz = geom[(size_t)p * 3 + 2];
        const int ix = (int)((gx + 50.0f) / 0.5f);
        const int iy = (int)((gy + 50.0f) / 0.5f);
        const int iz = (int)((gz + 10.0f) / 20.0f);
        if (ix >= 0 && ix < NXY && iy >= 0 && iy < NXY && iz == 0) {
            const int b = p / NP_PER_B;
            const float v = x[(size_t)p * 64 + lane];
            atomicAdd(&out[(((size_t)b * 64 + lane) * NXY + ix) * NXY + iy], v);
        }
    }
}

extern "C" void kernel_launch(void* const* d_in, const int* in_sizes, int n_in,
                              void* d_out, int out_size, void* d_ws, size_t ws_size,
                              hipStream_t stream) {
    const float* x    = (const float*)d_in[0];
    const float* geom = (const float*)d_in[1];
    float* out = (float*)d_out;

    // workspace carve-up
    char* ws = (char*)d_ws;
    size_t off = 0;
    int* counts    = (int*)(ws + off); off += (size_t)NBIN * 4;
    int* offsets   = (int*)(ws + off); off += (size_t)NBIN * 4;
    int* blocksums = (int*)(ws + off); off += (size_t)(NBLK_SCAN + 1) * 4;
    int* bins      = (int*)(ws + off); off += (size_t)NP * 4;
    unsigned int* sorted = (unsigned int*)(ws + off); off += (size_t)NP * 4;

    if (ws_size < off) {
        // fallback: direct atomic scatter
        hipMemsetAsync(out, 0, (size_t)out_size * sizeof(float), stream);
        lss_scatter_atomic<<<2048, 256, 0, stream>>>(x, geom, out);
        return;
    }

    hipMemsetAsync(counts, 0, (size_t)NBIN * 4, stream);

    const int pblocks = (NP + 255) / 256;                 // 5412
    bin_points<<<pblocks, 256, 0, stream>>>(geom, bins, counts);
    scan_blocks<<<NBLK_SCAN, 256, 0, stream>>>(counts, offsets, blocksums);
    scan_sums<<<1, 256, 0, stream>>>(blocksums, NBLK_SCAN);
    scatter_idx<<<pblocks, 256, 0, stream>>>(bins, offsets, blocksums, counts, sorted);
    gather6<<<2 * 8 * NXY, 256, 0, stream>>>(x, offsets, blocksums, sorted, out);
}

// Round 10
// 193.134 us; speedup vs baseline: 1.0994x; 1.0080x over previous
//
#include <hip/hip_runtime.h>
#include <hip/hip_bf16.h>

// LSS voxel pooling via inverted index (BEVPool-style), no atomics in gather.
//   x:    (B=8, N=6, D=41, H=16, W=44, C=64) f32
//   geom: (B, N, D, H, W, 3) f32
//   out:  (B, C=64, X=200, Y=200) f32
//
// bin = (b*200 + ix)*200 + iy,  kept iff 0<=ix<200, 0<=iy<200, iz==0
// (IEEE fp32 add + div + trunc-toward-zero matches reference .astype(int32))
//
// Pipeline:
//   A bin_points : histogram only (int atomics, L2) -- no bins[] array
//   B scan       : 2-level exclusive scan; blocksums[] separate (consumers add
//                  blocksums[bin>>8]); grand total at blocksums[NBLK_SCAN]
//   C scatter    : recomputes bin from geom (L3-hot); CSR slot via atomicSub
//   D gather7    : block = half (b,ix) row (100 bins). EQUAL-POINT SPLIT:
//                  the block's CSR range is split into 16 equal quarter-wave
//                  slices (zero intra-block imbalance). Interior runs flush
//                  to the LDS tile (exclusive by construction); head/tail
//                  partial runs go to a 32-slot scratch, merged serially by
//                  wave 0 (no LDS atomics). float4 lanes, 8-deep pipeline.

#define NP        1385472
#define NP_PER_B  173184      // N*D*H*W
#define NXY       200
#define NBIN      320000      // 8*200*200
#define NBLK_SCAN 1250        // NBIN/256 exactly
#define UNR       8           // point-steps in flight per quarter (4 pts/wave-step)
#define TSTRIDE   69          // tile row stride in floats (odd -> no bank conflict)

// ---------------- phase A: histogram ----------------
__global__ void bin_points(const float* __restrict__ geom,
                           int* __restrict__ counts) {
    int p = blockIdx.x * 256 + threadIdx.x;
    if (p >= NP) return;
    float gx = geom[(size_t)p * 3 + 0];
    float gy = geom[(size_t)p * 3 + 1];
    float gz = geom[(size_t)p * 3 + 2];
    int ix = (int)((gx + 50.0f) / 0.5f);
    int iy = (int)((gy + 50.0f) / 0.5f);
    int iz = (int)((gz + 10.0f) / 20.0f);
    if (ix >= 0 && ix < NXY && iy >= 0 && iy < NXY && iz == 0) {
        int b = p / NP_PER_B;
        atomicAdd(&counts[(b * NXY + ix) * NXY + iy], 1);
    }
}

// ---------------- phase B: exclusive scan of counts (2-level) ----------------
__global__ void scan_blocks(const int* __restrict__ counts,
                            int* __restrict__ offsets,
                            int* __restrict__ blocksums) {
    __shared__ int tmp[256];
    int i = blockIdx.x * 256 + threadIdx.x;
    int v = (i < NBIN) ? counts[i] : 0;
    tmp[threadIdx.x] = v;
    __syncthreads();
    for (int d = 1; d < 256; d <<= 1) {
        int t = (threadIdx.x >= d) ? tmp[threadIdx.x - d] : 0;
        __syncthreads();
        tmp[threadIdx.x] += t;
        __syncthreads();
    }
    if (i < NBIN) offsets[i] = tmp[threadIdx.x] - v;   // exclusive, block-local
    if (threadIdx.x == 255) blocksums[blockIdx.x] = tmp[255];
}

__global__ void scan_sums(int* __restrict__ blocksums, int nblocks) {
    __shared__ int tmp[256];
    __shared__ int carry;
    if (threadIdx.x == 0) carry = 0;
    __syncthreads();
    for (int base = 0; base < nblocks; base += 256) {
        int i = base + threadIdx.x;
        int v = (i < nblocks) ? blocksums[i] : 0;
        tmp[threadIdx.x] = v;
        __syncthreads();
        for (int d = 1; d < 256; d <<= 1) {
            int t = (threadIdx.x >= d) ? tmp[threadIdx.x - d] : 0;
            __syncthreads();
            tmp[threadIdx.x] += t;
            __syncthreads();
        }
        if (i < nblocks) blocksums[i] = tmp[threadIdx.x] - v + carry;  // exclusive
        __syncthreads();
        if (threadIdx.x == 255) carry += tmp[255];
        __syncthreads();
    }
    if (threadIdx.x == 0) blocksums[nblocks] = carry;   // grand total (kept pts)
}

// ---------------- phase C: scatter packed (pid,iy) into CSR ----------------
// bin recomputed from geom (no bins[] round-trip); counts consumed (atomicSub).
__global__ void scatter_idx(const float* __restrict__ geom,
                            const int* __restrict__ offsets,
                            const int* __restrict__ blocksums,
                            int* __restrict__ counts,
                            unsigned int* __restrict__ sorted) {
    int p = blockIdx.x * 256 + threadIdx.x;
    if (p >= NP) return;
    float gx = geom[(size_t)p * 3 + 0];
    float gy = geom[(size_t)p * 3 + 1];
    float gz = geom[(size_t)p * 3 + 2];
    int ix = (int)((gx + 50.0f) / 0.5f);
    int iy = (int)((gy + 50.0f) / 0.5f);
    int iz = (int)((gz + 10.0f) / 20.0f);
    if (ix >= 0 && ix < NXY && iy >= 0 && iy < NXY && iz == 0) {
        int b = p / NP_PER_B;
        int bin = (b * NXY + ix) * NXY + iy;
        int pos = atomicSub(&counts[bin], 1) - 1;        // [0, count)
        int dst = offsets[bin] + blocksums[bin >> 8] + pos;
        sorted[dst] = ((unsigned int)p << 8) | (unsigned int)iy;
    }
}

// ------- phase D: equal-split quarter-wave float4 gather, scratch merge -------
__global__ __launch_bounds__(256, 4) void gather7(const float* __restrict__ x,
                                                  const int* __restrict__ offsets,
                                                  const int* __restrict__ blocksums,
                                                  const unsigned int* __restrict__ packed,
                                                  float* __restrict__ out) {
    __shared__ float tile[100 * TSTRIDE];   // [iy_local][c]
    __shared__ float scr[32][64];           // 16 quarters x {head,tail} partials
    __shared__ int   scr_iy[32];
    for (int f = threadIdx.x; f < 100 * TSTRIDE; f += 256) tile[f] = 0.0f;
    if (threadIdx.x < 32) scr_iy[threadIdx.x] = -1;
    __syncthreads();

    const float4* __restrict__ x4 = (const float4*)x;

    const int bix   = blockIdx.x >> 1;        // b*200 + ix
    const int half  = blockIdx.x & 1;         // iy half
    const int hbase = half * 100;
    const int wave  = threadIdx.x >> 6;
    const int lane  = threadIdx.x & 63;
    const int q     = lane >> 4;              // quarter-wave 0..3
    const int sl    = lane & 15;              // channels 4*sl..4*sl+3
    const int t     = wave * 4 + q;           // block-quarter 0..15

    // block CSR range (100 consecutive bins), equal 16-way point split
    const int bin0 = bix * NXY + hbase;
    const int binE = bin0 + 100;
    const int rs = offsets[bin0] + blocksums[bin0 >> 8];
    const int re = (binE < NBIN) ? (offsets[binE] + blocksums[binE >> 8])
                                 : blocksums[NBLK_SCAN];
    const int n  = re - rs;
    const int ps = rs + ((n * t) >> 4);
    const int pe = rs + ((n * (t + 1)) >> 4);

    int   cur = -1;                 // current iy (uniform within quarter)
    bool  first = true;             // accumulator still holds the head run
    float ax = 0.f, ay = 0.f, az = 0.f, aw = 0.f;

    int i = ps;
    unsigned int pk[UNR];
#pragma unroll
    for (int u = 0; u < UNR; ++u) {
        int ii = i + u; ii = (ii < pe) ? ii : (pe - 1); ii = (ii < 0) ? 0 : ii;
        pk[u] = packed[ii];                        // clamped -> in-bounds
    }
    while (__any(i < pe)) {
        // UNR independent 1KB x loads (4 rows per wave instruction)
        float4 v[UNR];
#pragma unroll
        for (int u = 0; u < UNR; ++u) {
            const bool val = (i + u) < pe;
            const unsigned int pid = val ? (pk[u] >> 8) : 0u;
            v[u] = x4[(size_t)pid * 16 + sl];
        }
        // prefetch next pk batch (clamped, branchless)
        const int ni = i + UNR;
        unsigned int pk2[UNR];
#pragma unroll
        for (int u = 0; u < UNR; ++u) {
            int ii = ni + u; ii = (ii < pe) ? ii : (pe - 1); ii = (ii < 0) ? 0 : ii;
            pk2[u] = packed[ii];
        }
        // run-length accumulation; interior runs -> tile (exclusive),
        // head run -> scratch slot 2t
#pragma unroll
        for (int u = 0; u < UNR; ++u) {
            const bool val = (i + u) < pe;
            const int iyv  = val ? (int)(pk[u] & 0xFFu) : cur;
            const bool chg = (iyv != cur);
            if (chg && cur >= 0) {
                float* dst = first ? &scr[2 * t][4 * sl]
                                   : &tile[(cur - hbase) * TSTRIDE + 4 * sl];
                dst[0] = ax; dst[1] = ay; dst[2] = az; dst[3] = aw;
                if (first && sl == 0) scr_iy[2 * t] = cur;
                first = false;
            }
            const float mx = val ? v[u].x : 0.f;
            const float my = val ? v[u].y : 0.f;
            const float mz = val ? v[u].z : 0.f;
            const float mw = val ? v[u].w : 0.f;
            ax = chg ? v[u].x : ax + mx;          // chg implies val
            ay = chg ? v[u].y : ay + my;
            az = chg ? v[u].z : az + mz;
            aw = chg ? v[u].w : aw + mw;
            cur = chg ? iyv : cur;
        }
#pragma unroll
        for (int u = 0; u < UNR; ++u) pk[u] = pk2[u];
        i = ni;
    }
    // final flush: tail run -> scratch (slot 2t if it is also the head run)
    if (cur >= 0) {
        const int slot = first ? 2 * t : 2 * t + 1;
        float* dst = &scr[slot][4 * sl];
        dst[0] = ax; dst[1] = ay; dst[2] = az; dst[3] = aw;
        if (sl == 0) scr_iy[slot] = cur;
    }
    __syncthreads();

    // serial merge of <=32 boundary partials by wave 0 (no atomics)
    if (wave == 0) {
        for (int s = 0; s < 32; ++s) {
            const int iyv = scr_iy[s];
            if (iyv >= 0)
                tile[(iyv - hbase) * TSTRIDE + lane] += scr[s][lane];
        }
    }
    __syncthreads();

    // coalesced out-write: consecutive threads -> consecutive iy
    const int b  = bix / NXY;
    const int ix = bix % NXY;
    float* obase = out + (size_t)b * 64 * 40000 + (size_t)ix * 200 + hbase;
    for (int f = threadIdx.x; f < 64 * 100; f += 256) {
        const int c  = f / 100;
        const int iy = f % 100;
        obase[(size_t)c * 40000 + iy] = tile[iy * TSTRIDE + c];
    }
}

// ---------------- fallback (round-1): direct atomic scatter ----------------
__global__ void lss_scatter_atomic(const float* __restrict__ x,
                                   const float* __restrict__ geom,
                                   float* __restrict__ out) {
    const int lane   = threadIdx.x & 63;
    const int wave   = (blockIdx.x * blockDim.x + threadIdx.x) >> 6;
    const int nwaves = (gridDim.x * blockDim.x) >> 6;
    for (int p = wave; p < NP; p += nwaves) {
        const float gx = geom[(size_t)p * 3 + 0];
        const float gy = geom[(size_t)p * 3 + 1];
        const float gz = geom[(size_t)p * 3 + 2];
        const int ix = (int)((gx + 50.0f) / 0.5f);
        const int iy = (int)((gy + 50.0f) / 0.5f);
        const int iz = (int)((gz + 10.0f) / 20.0f);
        if (ix >= 0 && ix < NXY && iy >= 0 && iy < NXY && iz == 0) {
            const int b = p / NP_PER_B;
            const float v = x[(size_t)p * 64 + lane];
            atomicAdd(&out[(((size_t)b * 64 + lane) * NXY + ix) * NXY + iy], v);
        }
    }
}

extern "C" void kernel_launch(void* const* d_in, const int* in_sizes, int n_in,
                              void* d_out, int out_size, void* d_ws, size_t ws_size,
                              hipStream_t stream) {
    const float* x    = (const float*)d_in[0];
    const float* geom = (const float*)d_in[1];
    float* out = (float*)d_out;

    // workspace carve-up
    char* ws = (char*)d_ws;
    size_t off = 0;
    int* counts    = (int*)(ws + off); off += (size_t)NBIN * 4;
    int* offsets   = (int*)(ws + off); off += (size_t)NBIN * 4;
    int* blocksums = (int*)(ws + off); off += (size_t)(NBLK_SCAN + 1) * 4;
    unsigned int* sorted = (unsigned int*)(ws + off); off += (size_t)NP * 4;

    if (ws_size < off) {
        // fallback: direct atomic scatter
        hipMemsetAsync(out, 0, (size_t)out_size * sizeof(float), stream);
        lss_scatter_atomic<<<2048, 256, 0, stream>>>(x, geom, out);
        return;
    }

    hipMemsetAsync(counts, 0, (size_t)NBIN * 4, stream);

    const int pblocks = (NP + 255) / 256;                 // 5412
    bin_points<<<pblocks, 256, 0, stream>>>(geom, counts);
    scan_blocks<<<NBLK_SCAN, 256, 0, stream>>>(counts, offsets, blocksums);
    scan_sums<<<1, 256, 0, stream>>>(blocksums, NBLK_SCAN);
    scatter_idx<<<pblocks, 256, 0, stream>>>(geom, offsets, blocksums, counts, sorted);
    gather7<<<2 * 8 * NXY, 256, 0, stream>>>(x, offsets, blocksums, sorted, out);
}